// Round 1
// baseline (142.728 us; speedup 1.0000x reference)
//
#include <hip/hip_runtime.h>
#include <hip/hip_bf16.h>

// CoincidenceDetector: S[b,n] = sum_d |w_d| * [|q[b,d]-pt[n,d]|<5] * exp(-|dt|/3)
// pt = 20 - 15*sigmoid(patterns)
//
// Trick: exp(-|dt|/3) = min(Eq*Ip, Iq*Ep) with Eq=e^{q/3}, Ep=e^{pt/3} etc.
// -> no per-element transcendental; 6 full-rate VALU ops per element.
// Window |dt|<5  <=>  w*exp(-|dt|/3) > w*exp(-5/3)  (strict, matches ref).

static constexpr float kC2    = 0.48089834696298783f;   // 1/(3*ln2): e^{x/3} = 2^{x*kC2}
static constexpr float kTheta = 0.18887560283756183f;   // exp(-5/3)

#define B_     64
#define N_     16384
#define D_     256
#define NTILE  64      // n rows per block
#define DHALF  128     // d staged per half (2 halves)
#define THREADS 512    // 8 waves
#define BPW    8       // batches per wave (8 waves * 8 = 64)

__global__ void cd_precompute(const float* __restrict__ q,
                              const float* __restrict__ w,
                              float* __restrict__ Eq,
                              float* __restrict__ Iq,
                              float* __restrict__ thw) {
    int e = blockIdx.x * 256 + threadIdx.x;
    if (e < B_ * D_) {
        float qv = q[e];
        Eq[e] = exp2f(qv * kC2);
        Iq[e] = exp2f(-qv * kC2);
    }
    if (e < D_) thw[e] = kTheta * fabsf(w[e]);
}

__global__ __launch_bounds__(THREADS) void cd_main(
        const float* __restrict__ patterns,
        const float* __restrict__ weights,
        const float* __restrict__ Eq,
        const float* __restrict__ Iq,
        const float* __restrict__ thw,
        float* __restrict__ S) {
    // Swizzled LDS: pair-of-float4 (8 dword) granules XORed by (row&7) so the
    // per-lane row-major ds_read_b128 pattern is <=2-way bank conflict (free).
    __shared__ float sEp[NTILE * DHALF];   // 32 KB
    __shared__ float sIp[NTILE * DHALF];   // 32 KB  (total 64 KB)

    const int t  = threadIdx.x;
    const int wv = t >> 6;     // wave id 0..7
    const int l  = t & 63;     // lane = local n
    const int n0 = blockIdx.x * NTILE;

    float acc[BPW];
#pragma unroll
    for (int i = 0; i < BPW; ++i) acc[i] = 0.f;

    for (int h = 0; h < 2; ++h) {
        __syncthreads();   // protect LDS overwrite (h=1); harmless at h=0
        // ---- stage 64 x 128 half-tile: wEp = |w|*e^{pt/3}, wIp = |w|*e^{-pt/3}
#pragma unroll
        for (int it = 0; it < (NTILE * DHALF) / THREADS; ++it) {   // 16 iters
            int e   = it * THREADS + t;
            int row = e >> 7;          // 0..63
            int col = e & 127;         // 0..127
            float x  = patterns[(size_t)(n0 + row) * D_ + h * DHALF + col];
            float sg = 1.f / (1.f + __expf(-x));
            float pt = 20.f - 15.f * sg;
            float wa = fabsf(weights[h * DHALF + col]);
            float ep = wa * exp2f(pt * kC2);
            float ip = wa * exp2f(-pt * kC2);
            int pq  = col >> 3;        // 8-dword pair index 0..15
            int idx = row * DHALF + (((pq ^ (row & 7)) << 3) | (col & 7));
            sEp[idx] = ep;
            sIp[idx] = ip;
        }
        __syncthreads();

        const float* EqH = Eq  + h * DHALF;
        const float* IqH = Iq  + h * DHALF;
        const float* twH = thw + h * DHALF;

#pragma unroll 2
        for (int c = 0; c < DHALF / 8; ++c) {       // 16 chunks of 8 d
            int base = l * DHALF + ((c ^ (l & 7)) << 3);
            float4 e0 = *(const float4*)&sEp[base];
            float4 e1 = *(const float4*)&sEp[base + 4];
            float4 i0 = *(const float4*)&sIp[base];
            float4 i1 = *(const float4*)&sIp[base + 4];
            float epv[8] = {e0.x, e0.y, e0.z, e0.w, e1.x, e1.y, e1.z, e1.w};
            float ipv[8] = {i0.x, i0.y, i0.z, i0.w, i1.x, i1.y, i1.z, i1.w};
            float tw[8];
#pragma unroll
            for (int dd = 0; dd < 8; ++dd) tw[dd] = twH[c * 8 + dd];   // uniform -> s_load
#pragma unroll
            for (int bi = 0; bi < BPW; ++bi) {
                int b = wv * BPW + bi;
                const float* eqp = EqH + (size_t)b * D_ + c * 8;   // uniform -> s_load
                const float* iqp = IqH + (size_t)b * D_ + c * 8;
#pragma unroll
                for (int dd = 0; dd < 8; ++dd) {
                    float a  = eqp[dd] * ipv[dd];
                    float bb = iqp[dd] * epv[dd];
                    float k  = fminf(a, bb);
                    acc[bi] += (k > tw[dd]) ? k : 0.f;
                }
            }
        }
    }

    // coalesced store: lane = n
#pragma unroll
    for (int bi = 0; bi < BPW; ++bi) {
        int b = wv * BPW + bi;
        S[(size_t)b * N_ + n0 + l] = acc[bi];
    }
}

extern "C" void kernel_launch(void* const* d_in, const int* in_sizes, int n_in,
                              void* d_out, int out_size, void* d_ws, size_t ws_size,
                              hipStream_t stream) {
    const float* q        = (const float*)d_in[0];
    const float* patterns = (const float*)d_in[1];
    const float* weights  = (const float*)d_in[2];
    float* S = (float*)d_out;

    float* Eq  = (float*)d_ws;          // 64*256 f32
    float* Iq  = Eq + B_ * D_;          // 64*256 f32
    float* thw = Iq + B_ * D_;          // 256 f32   (total ~132 KB of ws)

    cd_precompute<<<(B_ * D_ + 255) / 256, 256, 0, stream>>>(q, weights, Eq, Iq, thw);
    cd_main<<<N_ / NTILE, THREADS, 0, stream>>>(patterns, weights, Eq, Iq, thw, S);
}